// Round 6
// baseline (2808.728 us; speedup 1.0000x reference)
//
#include <hip/hip_runtime.h>
#include <cstdint>
#include <cstddef>

typedef unsigned int   u32;
typedef unsigned short u16;
typedef unsigned long long u64;
typedef __attribute__((ext_vector_type(8))) short bf16x8;   // 8 bf16 = 4 VGPR
typedef __attribute__((ext_vector_type(4))) float f32x4;

#define B_  512
#define T_  168
#define H_  512

// ---------------- workspace layout (bytes). Requires ws_size >= 16MB + 8KB ----
#define OFF_U1P   (0u)                    // packed U1   bf16 [16kc][128ng][64][8]  (2MB)
#define OFF_UW2P  (2u*1024*1024)          // packed W2;U2 bf16 [32kc][128ng][64][8] (4MB)
#define OFF_H1    (6u*1024*1024)          // h1 ring, 8 slots x 512KB
#define OFF_H2    (14u*1024*1024)         // h2 ring, 2 slots x 512KB
#define OFF_FLAGS (16u*1024*1024)         // done counters (256B stride)
#define H_SLOT    262144u                 // u16 elems per slot = 32bg*16kc*64*8
#define NRING     8
#define FSTRIDE   64                      // ints per flag slot (256B)
#define SMEM_V6   (131072 + 6144 + 3072)  // B(128K) + hlds(6K) + wlds(3K)

__device__ __forceinline__ u16 f2bf(float v){              // RNE f32->bf16
  u32 u = __float_as_uint(v);
  return (u16)((u + 0x7fffu + ((u >> 16) & 1u)) >> 16);
}
__device__ __forceinline__ float bf2f(u16 b){ return __uint_as_float(((u32)b) << 16); }
__device__ __forceinline__ float sigm(float x){ return 1.f/(1.f + __expf(-x)); }
__device__ __forceinline__ float tanh_f(float x){
  float e = __expf(-2.f*fabsf(x));
  float t = (1.f - e)/(1.f + e);
  return (x < 0.f) ? -t : t;
}
__device__ __forceinline__ float sigm_f(float x){ return __fdividef(1.f, 1.f + __expf(-x)); }
__device__ __forceinline__ float tanh_ff(float x){
  float e = __expf(-2.f*fabsf(x));
  float t = __fdividef(1.f - e, 1.f + e);
  return (x < 0.f) ? -t : t;
}
// AGENT scope (sc1): bypasses non-coherent XCD L2s, write-back at LLC, relaxed
// ops emit no cache-maintenance. (r1: per-poll acquire = buffer_inv storm;
// r2: SYSTEM scope = HBM write-through; r4: VGPR 256 spill; r5 lesson: volume
// halved, time -4% => latency/barrier-bound, hence the v6 barrier-free K-loop.)
__device__ __forceinline__ void spin_ge(int* p, int target){
  while (__hip_atomic_load(p, __ATOMIC_RELAXED, __HIP_MEMORY_SCOPE_AGENT) < target)
    __builtin_amdgcn_s_sleep(1);
}
__device__ __forceinline__ void async_cp16(const void* g, void* l){
  __builtin_amdgcn_global_load_lds((const __attribute__((address_space(1))) u32*)g,
                                   (__attribute__((address_space(3))) u32*)l, 16, 0, 0);
}
__device__ __forceinline__ bf16x8 ring_ld16(const u16* p){
  union { u64 q[2]; bf16x8 v; } u;
  u.q[0] = __hip_atomic_load((const u64*)p,     __ATOMIC_RELAXED, __HIP_MEMORY_SCOPE_AGENT);
  u.q[1] = __hip_atomic_load(((const u64*)p)+1, __ATOMIC_RELAXED, __HIP_MEMORY_SCOPE_AGENT);
  return u.v;
}
__device__ __forceinline__ void ring_st16(u16* p, uint4 v){
  u64 lo = ((u64)v.y << 32) | v.x;
  u64 hi = ((u64)v.w << 32) | v.z;
  __hip_atomic_store((u64*)p,     lo, __ATOMIC_RELAXED, __HIP_MEMORY_SCOPE_AGENT);
  __hip_atomic_store(((u64*)p)+1, hi, __ATOMIC_RELAXED, __HIP_MEMORY_SCOPE_AGENT);
}

// ---------------- weight packing: B-operand fragment layout ------------------
__global__ void pack_w_kernel(const float* __restrict__ U1, const float* __restrict__ W2,
                              const float* __restrict__ U2, u16* __restrict__ U1p,
                              u16* __restrict__ UW2p)
{
  int idx = blockIdx.x*256 + threadIdx.x;
  int ln = idx & 63;
  int q8 = ((ln >> 4) << 3);
  int cl = ln & 15;
  if (idx < 16*128*64) {
    int kc = idx >> 13, ng = (idx >> 6) & 127;
    int row0 = kc*32 + q8, col = ng*16 + cl;
    u16* d = U1p + (size_t)idx*8;
    #pragma unroll
    for (int j=0;j<8;j++) d[j] = f2bf(U1[(size_t)(row0+j)*2048 + col]);
  } else {
    int i2 = idx - 16*128*64;
    if (i2 >= 32*128*64) return;
    int kc = i2 >> 13, ng = (i2 >> 6) & 127;
    int row0 = kc*32 + q8, col = ng*16 + cl;
    u16* d = UW2p + (size_t)i2*8;
    #pragma unroll
    for (int j=0;j<8;j++){
      int r = row0 + j;
      float v = (r < 512) ? W2[(size_t)r*2048 + col] : U2[(size_t)(r-512)*2048 + col];
      d[j] = f2bf(v);
    }
  }
}

__global__ void init_kernel(float* __restrict__ out, const float* __restrict__ fcb,
                            int* __restrict__ flags)
{
  int i = blockIdx.x*256 + threadIdx.x;
  if (i < 2048) flags[i] = 0;
  if (i < B_*T_) out[i] = fcb[0];
}

// ============================ v6: LDS-persistent B ===========================
// 256 blocks, 1/CU. L1: blk 0..127: bi=blk>>4 (64 rows), hj=blk&15 (32 cols).
// L2: blk 128..255: bi2=(blk-128)>>5 (128 rows), hj=(blk-128)&31 (16 cols).
// B (t-invariant) staged ONCE into 128KB LDS; K-loop is barrier-free: A is
// wave-private ring loads in an 8-deep register window, compiler-pipelined.
// 2 barriers/step total (spin broadcast + pack drain), was 12.

__device__ void run_l1_v6(char* smem, int blk, const float* __restrict__ inp,
                          const float* __restrict__ W1, const float* __restrict__ V,
                          const float* __restrict__ bias, char* __restrict__ ws)
{
  u16*  Bl   = (u16*)smem;                        // [16kc][8ngl][512]
  u16*  hlds = (u16*)(smem + 131072);             // 64 x 40
  float* wlds = (float*)(smem + 131072 + 6144);   // 4*32*6
  constexpr int RS = 40;
  const int tid = threadIdx.x, w = tid>>6, ln = tid&63, col = ln&15, quad = ln>>4;
  const int bi = blk >> 4, hj = blk & 15, h0 = hj*32, bg = bi*4 + w;

  const u16* Upak = (const u16*)(ws + OFF_U1P);
  const u16* H1r  = (const u16*)(ws + OFF_H1);
  u16* Hw = (u16*)(ws + OFF_H1);
  int* done1 = (int*)(ws + OFF_FLAGS) + bi*FSTRIDE;
  int* done2 = (int*)(ws + OFF_FLAGS) + 1024 + (bi>>1)*FSTRIDE;

  // stage all of B once (32 pieces/wave x 1KB)
  #pragma unroll
  for (int p=0;p<32;p++){
    int pid = w*32 + p, kc = pid>>3, ngl = pid&7;
    int ng = (ngl>>1)*32 + hj*2 + (ngl&1);
    async_cp16(Upak + ((size_t)(kc*128+ng)*64 + ln)*8, Bl + (size_t)pid*512);
  }
  for (int idx=tid; idx<4*32*6; idx+=256){
    int gate = idx/192, rem = idx%192, hcol = rem/6, k = rem%6;
    int gcol = gate*512 + h0 + hcol;
    wlds[idx] = (k==0)? bias[gcol] : (k<=4 ? V[(size_t)(k-1)*2048 + gcol] : W1[gcol]);
  }

  float c[8];
  #pragma unroll
  for (int i=0;i<8;i++) c[i] = 0.f;
  const f32x4 vzero = {0.f,0.f,0.f,0.f};

  for (int t=0; t<T_; t++){
    if (tid==0){
      if (t>0)      spin_ge(done1, 16*t);             // own cohort: h1[t-1] full-K ready
      if (t>=NRING) spin_ge(done2, 32*(t-NRING+1));   // ring back-pressure
      __builtin_amdgcn_fence(__ATOMIC_ACQUIRE, "workgroup");
    }
    __syncthreads();   // barrier 1 (also drains B-stage at t=0)

    f32x4 acc[8];
    #pragma unroll
    for (int i=0;i<8;i++) acc[i] = vzero;

    if (t > 0){
      const u16* ab = H1r + (size_t)((t-1)&7)*H_SLOT + (size_t)bg*16*512 + (size_t)ln*8;
      bf16x8 aw[8];
      #pragma unroll
      for (int i=0;i<8;i++) aw[i] = ring_ld16(ab + (size_t)i*512);
      #pragma unroll
      for (int kc=0; kc<16; kc++){
        bf16x8 av = aw[kc&7];
        if (kc < 8) aw[kc&7] = ring_ld16(ab + (size_t)(kc+8)*512);
        const u16* bb = Bl + (size_t)kc*8*512 + (size_t)ln*8;
        #pragma unroll
        for (int ngl=0; ngl<8; ngl++)
          acc[ngl] = __builtin_amdgcn_mfma_f32_16x16x32_bf16(
              av, *(const bf16x8*)(bb + (size_t)ngl*512), acc[ngl], 0,0,0);
      }
    }

    // epilogue (wave-local)
    float inv[4][5];
    #pragma unroll
    for (int r=0;r<4;r++){
      const float* ip = inp + ((size_t)(bi*64 + w*16 + quad*4 + r)*T_ + t)*5;
      #pragma unroll
      for (int k=0;k<5;k++) inv[r][k] = ip[k];
    }
    #pragma unroll
    for (int hg=0; hg<2; hg++){
      float wv[4][6];
      #pragma unroll
      for (int gate=0; gate<4; gate++){
        const float* wp = wlds + (size_t)(gate*32 + hg*16 + col)*6;
        #pragma unroll
        for (int k=0;k<6;k++) wv[gate][k] = wp[k];
      }
      #pragma unroll
      for (int r=0;r<4;r++){
        float gv[4];
        #pragma unroll
        for (int gate=0; gate<4; gate++){
          gv[gate] = acc[gate*2+hg][r] + wv[gate][0]
                   + inv[r][0]*wv[gate][1] + inv[r][1]*wv[gate][2]
                   + inv[r][2]*wv[gate][3] + inv[r][3]*wv[gate][4]
                   + inv[r][4]*wv[gate][5];
        }
        float ig=sigm_f(gv[0]), fg=sigm_f(gv[1]), gg=tanh_ff(gv[2]), og=sigm_f(gv[3]);
        float cn = fg*c[hg*4+r] + ig*gg;
        c[hg*4+r] = cn;
        hlds[(size_t)(w*16 + quad*4 + r)*RS + hg*16 + col] = f2bf(og*tanh_ff(cn));
      }
    }
    // pack: SAME-WAVE transpose via hlds (no barrier needed before read)
    {
      uint4 v = *(const uint4*)&hlds[(size_t)(w*16 + (ln&15))*RS + (ln>>4)*8];
      ring_st16(Hw + (size_t)(t&7)*H_SLOT + ((size_t)(bg*16 + hj)*64 + ln)*8, v);
    }
    __syncthreads();   // barrier 2: drains all waves' pack stores before release
    if (tid==0){
      __builtin_amdgcn_fence(__ATOMIC_RELEASE, "workgroup");
      __hip_atomic_fetch_add(done1, 1, __ATOMIC_RELAXED, __HIP_MEMORY_SCOPE_AGENT);
    }
  }
}

template<int KCEND>
__device__ __forceinline__ void l2_kloop(f32x4* accA, f32x4* accB, const u16* Bl,
                                         const u16* A1, const u16* A2,
                                         int bgA, int bgB, int ln)
{
  bf16x8 awA[8], awB[8];
  #pragma unroll
  for (int i=0;i<8;i++){
    awA[i] = ring_ld16(A1 + ((size_t)bgA*16 + i)*512 + (size_t)ln*8);
    awB[i] = ring_ld16(A1 + ((size_t)bgB*16 + i)*512 + (size_t)ln*8);
  }
  #pragma unroll
  for (int kc=0; kc<KCEND; kc++){
    bf16x8 avA = awA[kc&7], avB = awB[kc&7];
    if (kc+8 < KCEND){
      int k2 = kc+8;
      const u16* base = (k2 < 16) ? A1 : A2;
      int kcl = (k2 < 16) ? k2 : (k2-16);
      awA[kc&7] = ring_ld16(base + ((size_t)bgA*16 + kcl)*512 + (size_t)ln*8);
      awB[kc&7] = ring_ld16(base + ((size_t)bgB*16 + kcl)*512 + (size_t)ln*8);
    }
    const u16* bb = Bl + (size_t)kc*4*512 + (size_t)ln*8;
    #pragma unroll
    for (int ngl=0; ngl<4; ngl++){
      bf16x8 bf = *(const bf16x8*)(bb + (size_t)ngl*512);
      accA[ngl] = __builtin_amdgcn_mfma_f32_16x16x32_bf16(avA, bf, accA[ngl], 0,0,0);
      accB[ngl] = __builtin_amdgcn_mfma_f32_16x16x32_bf16(avB, bf, accB[ngl], 0,0,0);
    }
  }
}

__device__ void run_l2_v6(char* smem, int blk2, const float* __restrict__ inp,
                          const float* __restrict__ V, const float* __restrict__ bias,
                          const float* __restrict__ fcw, char* __restrict__ ws,
                          float* __restrict__ out)
{
  u16*  Bl   = (u16*)smem;                        // [32kc][4ngl][512]
  u16*  hlds = (u16*)(smem + 131072);             // 128 x 24
  float* wlds = (float*)(smem + 131072 + 6144);   // 4*16*6
  constexpr int RS = 24;
  const int tid = threadIdx.x, w = tid>>6, ln = tid&63, col = ln&15, quad = ln>>4;
  const int bi2 = blk2 >> 5, hj = blk2 & 31, h0 = hj*16;
  const int bgA = bi2*8 + w, bgB = bgA + 4;

  const u16* Upak = (const u16*)(ws + OFF_UW2P);
  const u16* H1r  = (const u16*)(ws + OFF_H1);
  const u16* H2r  = (const u16*)(ws + OFF_H2);
  u16* Hw = (u16*)(ws + OFF_H2);
  int* flags = (int*)(ws + OFF_FLAGS);
  int* d1a = flags + (2*bi2)*FSTRIDE;
  int* d1b = flags + (2*bi2+1)*FSTRIDE;
  int* done2 = flags + 1024 + bi2*FSTRIDE;

  #pragma unroll
  for (int p=0;p<32;p++){
    int pid = w*32 + p, kc = pid>>2, ngl = pid&3;
    int ng = ngl*32 + hj;
    async_cp16(Upak + ((size_t)(kc*128+ng)*64 + ln)*8, Bl + (size_t)pid*512);
  }
  for (int idx=tid; idx<4*16*6; idx+=256){
    int gate = idx/96, rem = idx%96, hcol = rem/6, k = rem%6;
    int gcol = gate*512 + h0 + hcol;
    wlds[idx] = (k==0)? bias[gcol] : (k<=4 ? V[(size_t)(k-1)*2048 + gcol] : 0.f);
  }
  const float fcwr = fcw[h0 + col];

  float c[8];
  #pragma unroll
  for (int i=0;i<8;i++) c[i] = 0.f;
  const f32x4 vzero = {0.f,0.f,0.f,0.f};

  for (int t=0; t<T_; t++){
    if (tid==0){
      spin_ge(d1a, 16*(t+1));                 // h1[t] ready (both L1 bi halves)
      spin_ge(d1b, 16*(t+1));
      if (t>0) spin_ge(done2, 32*t);          // own cohort: h2[t-1] ready
      __builtin_amdgcn_fence(__ATOMIC_ACQUIRE, "workgroup");
    }
    __syncthreads();   // barrier 1

    f32x4 accA[4], accB[4];
    #pragma unroll
    for (int i=0;i<4;i++){ accA[i] = vzero; accB[i] = vzero; }

    const u16* A1 = H1r + (size_t)(t&7)*H_SLOT;
    if (t > 0){
      const u16* A2 = H2r + (size_t)((t-1)&1)*H_SLOT;
      l2_kloop<32>(accA, accB, Bl, A1, A2, bgA, bgB, ln);
    } else {
      l2_kloop<16>(accA, accB, Bl, A1, A1, bgA, bgB, ln);
    }

    // epilogue
    float wv[4][5];
    #pragma unroll
    for (int gate=0; gate<4; gate++){
      const float* wp = wlds + (size_t)(gate*16 + col)*6;
      #pragma unroll
      for (int k=0;k<5;k++) wv[gate][k] = wp[k];
    }
    float fcp[2][4];
    #pragma unroll
    for (int sel=0; sel<2; sel++){
      const f32x4* ac = sel ? accB : accA;
      #pragma unroll
      for (int r=0;r<4;r++){
        const float* ip = inp + ((size_t)(bi2*128 + sel*64 + w*16 + quad*4 + r)*T_ + t)*5;
        float i0=ip[0], i1=ip[1], i2=ip[2], i3=ip[3];
        float gv[4];
        #pragma unroll
        for (int gate=0; gate<4; gate++){
          gv[gate] = ac[gate][r] + wv[gate][0]
                   + i0*wv[gate][1] + i1*wv[gate][2] + i2*wv[gate][3] + i3*wv[gate][4];
        }
        float ig=sigm_f(gv[0]), fg=sigm_f(gv[1]), gg=tanh_ff(gv[2]), og=sigm_f(gv[3]);
        float cn = fg*c[sel*4+r] + ig*gg;
        c[sel*4+r] = cn;
        float h = og*tanh_ff(cn);
        fcp[sel][r] = h*fcwr;
        hlds[(size_t)(sel*64 + w*16 + quad*4 + r)*RS + col] = f2bf(h);
      }
    }
    #pragma unroll
    for (int sel=0; sel<2; sel++){
      #pragma unroll
      for (int r=0;r<4;r++){
        float v = fcp[sel][r];
        #pragma unroll
        for (int m=1;m<16;m<<=1) v += __shfl_xor(v, m, 16);
        if (col == 0)
          atomicAdd(&out[(size_t)(bi2*128 + sel*64 + w*16 + quad*4 + r)*T_ + t], v);
      }
    }
    // pack: same-wave transpose. Block cols = half a kc tile (kc=hj>>1, half hj&1)
    {
      int sel = ln>>5, ch = (ln>>4)&1, m = ln&15;
      uint4 v = *(const uint4*)&hlds[(size_t)(sel*64 + w*16 + m)*RS + ch*8];
      int lp = ((hj&1)*2 + ch)*16 + m;
      int bgx = bi2*8 + sel*4 + w;
      ring_st16(Hw + (size_t)(t&1)*H_SLOT + ((size_t)(bgx*16 + (hj>>1))*64 + lp)*8, v);
    }
    __syncthreads();   // barrier 2
    if (tid==0){
      __builtin_amdgcn_fence(__ATOMIC_RELEASE, "workgroup");
      __hip_atomic_fetch_add(done2, 1, __ATOMIC_RELAXED, __HIP_MEMORY_SCOPE_AGENT);
    }
  }
}

__global__ void __launch_bounds__(256, 1)
lstm_main_v6(const float* __restrict__ inp, const float* __restrict__ W1,
             const float* __restrict__ V1, const float* __restrict__ b1,
             const float* __restrict__ V2, const float* __restrict__ b2,
             const float* __restrict__ fcw, char* __restrict__ ws, float* __restrict__ out)
{
  extern __shared__ char smem[];
  int blk = blockIdx.x;
  if (blk < 128) run_l1_v6(smem, blk, inp, W1, V1, b1, ws);
  else           run_l2_v6(smem, blk-128, inp, V2, b2, fcw, ws, out);
}

// ===================== v5 fallback (proven 2582us path) ======================
template<int LAYER>
__device__ __forceinline__ void stage_B(u16* buf, const u16* __restrict__ Upak,
                                        int hj, int g, int w, int ln)
{
  constexpr int NGW = (LAYER==1)?16:8;
  constexpr int GKC = (LAYER==1)?2:4;
  #pragma unroll
  for (int p=0;p<8;p++){
    int pid = w*8 + p;
    int kci = pid / NGW;
    int ngl = pid % NGW;
    int gate = ngl / (NGW/4);
    int sub  = ngl % (NGW/4);
    int ng   = gate*32 + hj*(NGW/4) + sub;
    int kc   = g*GKC + kci;
    const u16* src = Upak + ((size_t)(kc*128 + ng)*64 + ln)*8;
    u16* dst = buf + (size_t)(kci*NGW + ngl)*512;
    async_cp16(src, dst);
  }
}

template<int LAYER>
__device__ __forceinline__ void preload_A(bf16x8* areg, const u16* __restrict__ A1,
                                          const u16* __restrict__ A2, int bg, int g, int ln)
{
  constexpr int GKC = (LAYER==1)?2:4;
  #pragma unroll
  for (int kci=0;kci<GKC;kci++){
    int kc = g*GKC + kci;
    const u16* base = A1; int kcl = kc;
    if (LAYER==2 && kc >= 16){ base = A2; kcl = kc - 16; }
    areg[kci] = ring_ld16(base + ((size_t)bg*16 + kcl)*512 + (size_t)ln*8);
  }
}

template<int LAYER>
__device__ void run_layer(u16 (*Bbuf)[16384], int blk,
                          const float* __restrict__ inp,
                          const float* __restrict__ W1,
                          const float* __restrict__ V,
                          const float* __restrict__ bias,
                          const float* __restrict__ fcw,
                          char* __restrict__ ws,
                          float* __restrict__ out)
{
  constexpr int HT  = (LAYER==1)?64:32;
  constexpr int HGN = (LAYER==1)?4:2;
  constexpr int NGW = (LAYER==1)?16:8;
  constexpr int GKC = (LAYER==1)?2:4;
  constexpr int RS  = (LAYER==1)?72:40;
  constexpr int KCP = (LAYER==1)?2:1;
  constexpr int NPIECE = 4*KCP;

  const int tid = threadIdx.x;
  const int w    = tid >> 6;
  const int ln   = tid & 63;
  const int col  = ln & 15;
  const int quad = ln >> 4;
  const int bi = (LAYER==1) ? (blk >> 3) : ((blk-64) >> 4);
  const int hj = (LAYER==1) ? (blk & 7)  : ((blk-64) & 15);
  const int h0 = hj * HT;
  const int bg = bi*4 + w;

  const u16* Upak = (const u16*)(ws + ((LAYER==1)?OFF_U1P:OFF_UW2P));
  const u16* H1r  = (const u16*)(ws + OFF_H1);
  const u16* H2r  = (const u16*)(ws + OFF_H2);
  u16* Hw  = (u16*)(ws + ((LAYER==1)?OFF_H1:OFF_H2));
  int* done1 = (int*)(ws + OFF_FLAGS);
  int* done2 = (int*)(ws + OFF_FLAGS) + 1024;
  u16* hlds  = &Bbuf[0][0];

  float fcwr[HGN];
  if (LAYER==2){
    #pragma unroll
    for (int hg=0; hg<HGN; hg++) fcwr[hg] = fcw[h0 + hg*16 + col];
  }
  float c[HGN*4];
  #pragma unroll
  for (int i=0;i<HGN*4;i++) c[i] = 0.f;
  const f32x4 vzero = {0.f,0.f,0.f,0.f};

  if (LAYER==2) stage_B<LAYER>(Bbuf[0], Upak, hj, 0, w, ln);

  for (int t=0; t<T_; t++){
    if (tid == 0){
      if (LAYER==1){
        if (t > 0)      spin_ge(&done1[bi*FSTRIDE], 8*t);
        if (t >= NRING) spin_ge(&done2[bi*FSTRIDE], 16*(t-NRING+1));
      } else {
        spin_ge(&done1[bi*FSTRIDE], 8*(t+1));
        if (t > 0) spin_ge(&done2[bi*FSTRIDE], 16*t);
      }
      __builtin_amdgcn_fence(__ATOMIC_ACQUIRE, "workgroup");
    }
    __syncthreads();

    f32x4 acc[NGW];
    #pragma unroll
    for (int i=0;i<NGW;i++) acc[i] = vzero;

    const int ngroups = (LAYER==1) ? (t>0 ? 8 : 0) : (t>0 ? 8 : 4);
    if (ngroups > 0){
      const u16* A1; const u16* A2 = nullptr;
      if (LAYER==1) A1 = H1r + (size_t)((t-1)%NRING)*H_SLOT;
      else { A1 = H1r + (size_t)(t%NRING)*H_SLOT;
             if (t>0) A2 = H2r + (size_t)((t-1)&1)*H_SLOT; }

      bf16x8 acur[GKC], anxt[GKC];
      preload_A<LAYER>(acur, A1, A2, bg, 0, ln);
      __syncthreads();
      for (int g=0; g<ngroups; g++){
        if (g+1 < ngroups){
          stage_B<LAYER>(Bbuf[(g+1)&1], Upak, hj, g+1, w, ln);
          preload_A<LAYER>(anxt, A1, A2, bg, g+1, ln);
        }
        #pragma unroll
        for (int kci=0; kci<GKC; kci++){
          const bf16x8 ah = acur[kci];
          #pragma unroll
          for (int ngl=0; ngl<NGW; ngl++){
            const bf16x8 bf = *(const bf16x8*)&Bbuf[g&1][(size_t)(kci*NGW+ngl)*512 + ln*8];
            acc[ngl] = __builtin_amdgcn_mfma_f32_16x16x32_bf16(ah, bf, acc[ngl], 0, 0, 0);
          }
        }
        #pragma unroll
        for (int i=0;i<GKC;i++) acur[i] = anxt[i];
        __syncthreads();
      }
    }

    float inv[4][5];
    #pragma unroll
    for (int r=0;r<4;r++){
      const float* ip = inp + ((size_t)(bi*64 + w*16 + quad*4 + r)*T_ + t)*5;
      #pragma unroll
      for (int k=0;k<5;k++) inv[r][k] = ip[k];
    }
    float fcp[4] = {0.f,0.f,0.f,0.f};
    #pragma unroll
    for (int hg=0; hg<HGN; hg++){
      float wv[4][6];
      #pragma unroll
      for (int gate=0; gate<4; gate++){
        int gcol = gate*512 + h0 + hg*16 + col;
        wv[gate][0] = bias[gcol];
        wv[gate][1] = V[gcol];
        wv[gate][2] = V[2048 + gcol];
        wv[gate][3] = V[4096 + gcol];
        wv[gate][4] = V[6144 + gcol];
        wv[gate][5] = (LAYER==1) ? W1[gcol] : 0.f;
      }
      #pragma unroll
      for (int r=0;r<4;r++){
        float gv[4];
        #pragma unroll
        for (int gate=0; gate<4; gate++){
          float p = wv[gate][0]
                  + inv[r][0]*wv[gate][1] + inv[r][1]*wv[gate][2]
                  + inv[r][2]*wv[gate][3] + inv[r][3]*wv[gate][4];
          if (LAYER==1) p += inv[r][4]*wv[gate][5];
          gv[gate] = acc[gate*HGN + hg][r] + p;
        }
        float ig = sigm(gv[0]);
        float fg = sigm(gv[1]);
        float gg = tanh_f(gv[2]);
        float og = sigm(gv[3]);
        float cn = fg*c[hg*4+r] + ig*gg;
        c[hg*4+r] = cn;
        float h = og*tanh_f(cn);
        if (LAYER==2) fcp[r] += h*fcwr[hg];
        int bl = w*16 + quad*4 + r;
        int hc = hg*16 + col;
        hlds[bl*RS + hc] = f2bf(h);
      }
    }
    if (LAYER==2){
      #pragma unroll
      for (int r=0;r<4;r++){
        #pragma unroll
        for (int m=1;m<16;m<<=1) fcp[r] += __shfl_xor(fcp[r], m, 16);
      }
      if (col == 0){
        #pragma unroll
        for (int r=0;r<4;r++)
          atomicAdd(&out[(size_t)(bi*64 + w*16 + quad*4 + r)*T_ + t], fcp[r]);
      }
    }
    __syncthreads();

    {
      u16* dst = Hw + (size_t)((LAYER==1) ? (t % NRING) : (t & 1))*H_SLOT;
      #pragma unroll
      for (int it=0; it<(NPIECE*64+255)/256; it++){
        int cidx = tid + it*256;
        if (cidx < NPIECE*64){
          int piece = cidx >> 6, lp = cidx & 63;
          int bgi, kci;
          if (LAYER==1){ bgi = (piece >> 1) & 3; kci = piece & 1; }
          else         { bgi = piece & 3;        kci = 0; }
          int row = bgi*16 + (lp & 15);
          int hc  = kci*32 + ((lp >> 4) << 3);
          uint4 v = *(const uint4*)&hlds[(size_t)row*RS + hc];
          int kcg = (LAYER==1) ? (hj*2 + kci) : hj;
          ring_st16(&dst[(((size_t)(bi*4 + bgi)*16 + kcg)*64 + lp)*8], v);
        }
      }
    }
    __syncthreads();
    if (tid == 0){
      __builtin_amdgcn_fence(__ATOMIC_RELEASE, "workgroup");
      int* dp = (LAYER==1) ? &done1[bi*FSTRIDE] : &done2[bi*FSTRIDE];
      __hip_atomic_fetch_add(dp, 1, __ATOMIC_RELAXED, __HIP_MEMORY_SCOPE_AGENT);
    }
    if (t+1 < T_) stage_B<LAYER>(Bbuf[0], Upak, hj, 0, w, ln);
  }
}

__global__ void __launch_bounds__(256, 1)
lstm_main_v5(const float* __restrict__ inp, const float* __restrict__ W1,
             const float* __restrict__ V1, const float* __restrict__ b1,
             const float* __restrict__ V2, const float* __restrict__ b2,
             const float* __restrict__ fcw, char* __restrict__ ws, float* __restrict__ out)
{
  __shared__ __align__(16) u16 Bbuf[2][16384];
  int blk = blockIdx.x;
  if (blk < 64) run_layer<1>(Bbuf, blk, inp, W1, V1, b1, nullptr, ws, out);
  else          run_layer<2>(Bbuf, blk, inp, nullptr, V2, b2, fcw, ws, out);
}

extern "C" void kernel_launch(void* const* d_in, const int* in_sizes, int n_in,
                              void* d_out, int out_size, void* d_ws, size_t ws_size,
                              hipStream_t stream) {
  const float* inp = (const float*)d_in[0];
  const float* W1  = (const float*)d_in[1];
  const float* U1  = (const float*)d_in[2];
  const float* V1  = (const float*)d_in[3];
  const float* b1  = (const float*)d_in[4];
  const float* W2  = (const float*)d_in[5];
  const float* U2  = (const float*)d_in[6];
  const float* V2  = (const float*)d_in[7];
  const float* b2  = (const float*)d_in[8];
  const float* fcw = (const float*)d_in[9];
  const float* fcb = (const float*)d_in[10];
  char* ws = (char*)d_ws;
  float* out = (float*)d_out;

  pack_w_kernel<<<1536, 256, 0, stream>>>(U1, W2, U2,
      (u16*)(ws + OFF_U1P), (u16*)(ws + OFF_UW2P));
  init_kernel<<<(B_*T_ + 255)/256, 256, 0, stream>>>(out, fcb, (int*)(ws + OFF_FLAGS));

  // CDNA4 allows up to 160KB LDS per workgroup; probe the device (host-side,
  // capture-safe) and take the barrier-free persistent-B kernel if it fits,
  // else fall back to the proven v5 path.
  int dev = 0; (void)hipGetDevice(&dev);
  int maxShm = 0;
  (void)hipDeviceGetAttribute(&maxShm, hipDeviceAttributeMaxSharedMemoryPerBlock, dev);
  if (maxShm >= SMEM_V6) {
    (void)hipFuncSetAttribute((const void*)lstm_main_v6,
                              hipFuncAttributeMaxDynamicSharedMemorySize, SMEM_V6);
    lstm_main_v6<<<256, 256, SMEM_V6, stream>>>(inp, W1, V1, b1, V2, b2, fcw, ws, out);
  } else {
    lstm_main_v5<<<192, 256, 0, stream>>>(inp, W1, V1, b1, V2, b2, fcw, ws, out);
  }
}

// Round 7
// 2301.104 us; speedup vs baseline: 1.2206x; 1.2206x over previous
//
#include <hip/hip_runtime.h>
#include <cstdint>
#include <cstddef>

typedef unsigned int   u32;
typedef unsigned short u16;
typedef unsigned long long u64;
typedef __attribute__((ext_vector_type(8))) short bf16x8;   // 8 bf16 = 4 VGPR
typedef __attribute__((ext_vector_type(4))) float f32x4;

#define B_  512
#define T_  168
#define H_  512

// ---------------- workspace layout (bytes). Requires ws_size >= 16MB + 8KB ----
#define OFF_U1P   (0u)                    // packed U1   bf16 [16kc][128ng][64][8]  (2MB)
#define OFF_UW2P  (2u*1024*1024)          // packed W2;U2 bf16 [32kc][128ng][64][8] (4MB)
#define OFF_H1    (6u*1024*1024)          // h1 ring, 8 slots x 512KB
#define OFF_H2    (14u*1024*1024)         // h2 ring, 2 slots x 512KB
#define OFF_FLAGS (16u*1024*1024)         // done counters (256B stride)
#define H_SLOT    262144u                 // u16 elems per slot = 32bg*16kc*64*8
#define NRING     8
#define FSTRIDE   64                      // ints per flag slot (256B)
#define SMEM_V6   (131072 + 6144 + 3072)  // B(128K) + hlds(6K) + wlds(3K)

__device__ __forceinline__ u16 f2bf(float v){              // RNE f32->bf16
  u32 u = __float_as_uint(v);
  return (u16)((u + 0x7fffu + ((u >> 16) & 1u)) >> 16);
}
__device__ __forceinline__ float bf2f(u16 b){ return __uint_as_float(((u32)b) << 16); }
__device__ __forceinline__ float sigm(float x){ return 1.f/(1.f + __expf(-x)); }
__device__ __forceinline__ float tanh_f(float x){
  float e = __expf(-2.f*fabsf(x));
  float t = (1.f - e)/(1.f + e);
  return (x < 0.f) ? -t : t;
}
__device__ __forceinline__ float sigm_f(float x){ return __fdividef(1.f, 1.f + __expf(-x)); }
__device__ __forceinline__ float tanh_ff(float x){
  float e = __expf(-2.f*fabsf(x));
  float t = __fdividef(1.f - e, 1.f + e);
  return (x < 0.f) ? -t : t;
}
// r7 memory model:
//  - polls: relaxed sc1 atomic loads (no cache maintenance while spinning -- r1)
//  - ring STORES: relaxed sc1 (direct to LLC, no wbl2; r2 showed SYSTEM=HBM)
//  - ring LOADS: PLAIN CACHED loads. Freshness from ONE agent-acquire fence
//    (buffer_inv) per step after spin success. v6 kept weights in LDS, so the
//    XCD L2 holds nothing hot -> per-step inv is cheap, and the first same-XCD
//    reader fills L2 for its ~15 co-located cohort siblings (sc1 loads made
//    that sharing impossible -- the r3..r6 ~16us/step invariant).
__device__ __forceinline__ void spin_ge(int* p, int target){
  while (__hip_atomic_load(p, __ATOMIC_RELAXED, __HIP_MEMORY_SCOPE_AGENT) < target)
    __builtin_amdgcn_s_sleep(1);
}
__device__ __forceinline__ void async_cp16(const void* g, void* l){
  __builtin_amdgcn_global_load_lds((const __attribute__((address_space(1))) u32*)g,
                                   (__attribute__((address_space(3))) u32*)l, 16, 0, 0);
}
__device__ __forceinline__ bf16x8 plain_ld16(const u16* p){   // cached, pipelined
  return *(const bf16x8*)p;
}
__device__ __forceinline__ bf16x8 ring_ld16(const u16* p){    // v5 fallback path
  union { u64 q[2]; bf16x8 v; } u;
  u.q[0] = __hip_atomic_load((const u64*)p,     __ATOMIC_RELAXED, __HIP_MEMORY_SCOPE_AGENT);
  u.q[1] = __hip_atomic_load(((const u64*)p)+1, __ATOMIC_RELAXED, __HIP_MEMORY_SCOPE_AGENT);
  return u.v;
}
__device__ __forceinline__ void ring_st16(u16* p, uint4 v){
  u64 lo = ((u64)v.y << 32) | v.x;
  u64 hi = ((u64)v.w << 32) | v.z;
  __hip_atomic_store((u64*)p,     lo, __ATOMIC_RELAXED, __HIP_MEMORY_SCOPE_AGENT);
  __hip_atomic_store(((u64*)p)+1, hi, __ATOMIC_RELAXED, __HIP_MEMORY_SCOPE_AGENT);
}

// ---------------- weight packing: B-operand fragment layout ------------------
__global__ void pack_w_kernel(const float* __restrict__ U1, const float* __restrict__ W2,
                              const float* __restrict__ U2, u16* __restrict__ U1p,
                              u16* __restrict__ UW2p)
{
  int idx = blockIdx.x*256 + threadIdx.x;
  int ln = idx & 63;
  int q8 = ((ln >> 4) << 3);
  int cl = ln & 15;
  if (idx < 16*128*64) {
    int kc = idx >> 13, ng = (idx >> 6) & 127;
    int row0 = kc*32 + q8, col = ng*16 + cl;
    u16* d = U1p + (size_t)idx*8;
    #pragma unroll
    for (int j=0;j<8;j++) d[j] = f2bf(U1[(size_t)(row0+j)*2048 + col]);
  } else {
    int i2 = idx - 16*128*64;
    if (i2 >= 32*128*64) return;
    int kc = i2 >> 13, ng = (i2 >> 6) & 127;
    int row0 = kc*32 + q8, col = ng*16 + cl;
    u16* d = UW2p + (size_t)i2*8;
    #pragma unroll
    for (int j=0;j<8;j++){
      int r = row0 + j;
      float v = (r < 512) ? W2[(size_t)r*2048 + col] : U2[(size_t)(r-512)*2048 + col];
      d[j] = f2bf(v);
    }
  }
}

__global__ void init_kernel(float* __restrict__ out, const float* __restrict__ fcb,
                            int* __restrict__ flags)
{
  int i = blockIdx.x*256 + threadIdx.x;
  if (i < 2048) flags[i] = 0;
  if (i < B_*T_) out[i] = fcb[0];
}

// ============================ v7: LDS-persistent B ===========================
// 256 blocks, 1/CU. XCD-cohort swizzle (blk%8 = XCD heuristic, perf-only):
// L1: blk 0..127:   bi  = blk & 7  (64 rows),  hj = blk >> 3 (32 cols) -> all
//     16 hj-blocks of a bi share one XCD => h1 reads hit local L2 after first.
// L2: blk 128..255: bi2 = blk2 & 3 (128 rows), hj = blk2 >> 2 (16 cols) ->
//     32 blocks of a bi2 land on XCDs {bi2, bi2+4}, 16 sharers each.
// K-loop barrier-free; ring reads are plain cached loads fenced once per step.

__device__ void run_l1_v6(char* smem, int blk, const float* __restrict__ inp,
                          const float* __restrict__ W1, const float* __restrict__ V,
                          const float* __restrict__ bias, char* __restrict__ ws)
{
  u16*  Bl   = (u16*)smem;                        // [16kc][8ngl][512]
  u16*  hlds = (u16*)(smem + 131072);             // 64 x 40
  float* wlds = (float*)(smem + 131072 + 6144);   // 4*32*6
  constexpr int RS = 40;
  const int tid = threadIdx.x, w = tid>>6, ln = tid&63, col = ln&15, quad = ln>>4;
  const int bi = blk & 7, hj = blk >> 3, h0 = hj*32, bg = bi*4 + w;

  const u16* Upak = (const u16*)(ws + OFF_U1P);
  const u16* H1r  = (const u16*)(ws + OFF_H1);
  u16* Hw = (u16*)(ws + OFF_H1);
  int* done1 = (int*)(ws + OFF_FLAGS) + bi*FSTRIDE;
  int* done2 = (int*)(ws + OFF_FLAGS) + 1024 + (bi>>1)*FSTRIDE;

  // stage all of B once (32 pieces/wave x 1KB)
  #pragma unroll
  for (int p=0;p<32;p++){
    int pid = w*32 + p, kc = pid>>3, ngl = pid&7;
    int ng = (ngl>>1)*32 + hj*2 + (ngl&1);
    async_cp16(Upak + ((size_t)(kc*128+ng)*64 + ln)*8, Bl + (size_t)pid*512);
  }
  for (int idx=tid; idx<4*32*6; idx+=256){
    int gate = idx/192, rem = idx%192, hcol = rem/6, k = rem%6;
    int gcol = gate*512 + h0 + hcol;
    wlds[idx] = (k==0)? bias[gcol] : (k<=4 ? V[(size_t)(k-1)*2048 + gcol] : W1[gcol]);
  }

  float c[8];
  #pragma unroll
  for (int i=0;i<8;i++) c[i] = 0.f;
  const f32x4 vzero = {0.f,0.f,0.f,0.f};

  for (int t=0; t<T_; t++){
    if (tid==0){
      if (t>0)      spin_ge(done1, 16*t);             // own cohort: h1[t-1] full-K ready
      if (t>=NRING) spin_ge(done2, 32*(t-NRING+1));   // ring back-pressure
      // ONE agent-acquire per step: buffer_inv makes the subsequent PLAIN ring
      // loads (all waves, ordered by the barrier) read fresh LLC data.
      __builtin_amdgcn_fence(__ATOMIC_ACQUIRE, "agent");
    }
    __syncthreads();   // barrier 1 (drains B-stage at t=0; orders inv for all waves)

    f32x4 acc[8];
    #pragma unroll
    for (int i=0;i<8;i++) acc[i] = vzero;

    if (t > 0){
      const u16* ab = H1r + (size_t)((t-1)&7)*H_SLOT + (size_t)bg*16*512 + (size_t)ln*8;
      bf16x8 aw[8];
      #pragma unroll
      for (int i=0;i<8;i++) aw[i] = plain_ld16(ab + (size_t)i*512);
      #pragma unroll
      for (int kc=0; kc<16; kc++){
        bf16x8 av = aw[kc&7];
        if (kc < 8) aw[kc&7] = plain_ld16(ab + (size_t)(kc+8)*512);
        const u16* bb = Bl + (size_t)kc*8*512 + (size_t)ln*8;
        #pragma unroll
        for (int ngl=0; ngl<8; ngl++)
          acc[ngl] = __builtin_amdgcn_mfma_f32_16x16x32_bf16(
              av, *(const bf16x8*)(bb + (size_t)ngl*512), acc[ngl], 0,0,0);
      }
    }

    // epilogue (wave-local)
    float inv[4][5];
    #pragma unroll
    for (int r=0;r<4;r++){
      const float* ip = inp + ((size_t)(bi*64 + w*16 + quad*4 + r)*T_ + t)*5;
      #pragma unroll
      for (int k=0;k<5;k++) inv[r][k] = ip[k];
    }
    #pragma unroll
    for (int hg=0; hg<2; hg++){
      float wv[4][6];
      #pragma unroll
      for (int gate=0; gate<4; gate++){
        const float* wp = wlds + (size_t)(gate*32 + hg*16 + col)*6;
        #pragma unroll
        for (int k=0;k<6;k++) wv[gate][k] = wp[k];
      }
      #pragma unroll
      for (int r=0;r<4;r++){
        float gv[4];
        #pragma unroll
        for (int gate=0; gate<4; gate++){
          gv[gate] = acc[gate*2+hg][r] + wv[gate][0]
                   + inv[r][0]*wv[gate][1] + inv[r][1]*wv[gate][2]
                   + inv[r][2]*wv[gate][3] + inv[r][3]*wv[gate][4]
                   + inv[r][4]*wv[gate][5];
        }
        float ig=sigm_f(gv[0]), fg=sigm_f(gv[1]), gg=tanh_ff(gv[2]), og=sigm_f(gv[3]);
        float cn = fg*c[hg*4+r] + ig*gg;
        c[hg*4+r] = cn;
        hlds[(size_t)(w*16 + quad*4 + r)*RS + hg*16 + col] = f2bf(og*tanh_ff(cn));
      }
    }
    // pack: SAME-WAVE transpose via hlds (no barrier needed before read)
    {
      uint4 v = *(const uint4*)&hlds[(size_t)(w*16 + (ln&15))*RS + (ln>>4)*8];
      ring_st16(Hw + (size_t)(t&7)*H_SLOT + ((size_t)(bg*16 + hj)*64 + ln)*8, v);
    }
    __syncthreads();   // barrier 2: drains all waves' pack stores before release
    if (tid==0){
      __builtin_amdgcn_fence(__ATOMIC_RELEASE, "workgroup");
      __hip_atomic_fetch_add(done1, 1, __ATOMIC_RELAXED, __HIP_MEMORY_SCOPE_AGENT);
    }
  }
}

template<int KCEND>
__device__ __forceinline__ void l2_kloop(f32x4* accA, f32x4* accB, const u16* Bl,
                                         const u16* A1, const u16* A2,
                                         int bgA, int bgB, int ln)
{
  bf16x8 awA[8], awB[8];
  #pragma unroll
  for (int i=0;i<8;i++){
    awA[i] = plain_ld16(A1 + ((size_t)bgA*16 + i)*512 + (size_t)ln*8);
    awB[i] = plain_ld16(A1 + ((size_t)bgB*16 + i)*512 + (size_t)ln*8);
  }
  #pragma unroll
  for (int kc=0; kc<KCEND; kc++){
    bf16x8 avA = awA[kc&7], avB = awB[kc&7];
    if (kc+8 < KCEND){
      int k2 = kc+8;
      const u16* base = (k2 < 16) ? A1 : A2;
      int kcl = (k2 < 16) ? k2 : (k2-16);
      awA[kc&7] = plain_ld16(base + ((size_t)bgA*16 + kcl)*512 + (size_t)ln*8);
      awB[kc&7] = plain_ld16(base + ((size_t)bgB*16 + kcl)*512 + (size_t)ln*8);
    }
    const u16* bb = Bl + (size_t)kc*4*512 + (size_t)ln*8;
    #pragma unroll
    for (int ngl=0; ngl<4; ngl++){
      bf16x8 bf = *(const bf16x8*)(bb + (size_t)ngl*512);
      accA[ngl] = __builtin_amdgcn_mfma_f32_16x16x32_bf16(avA, bf, accA[ngl], 0,0,0);
      accB[ngl] = __builtin_amdgcn_mfma_f32_16x16x32_bf16(avB, bf, accB[ngl], 0,0,0);
    }
  }
}

__device__ void run_l2_v6(char* smem, int blk2, const float* __restrict__ inp,
                          const float* __restrict__ V, const float* __restrict__ bias,
                          const float* __restrict__ fcw, char* __restrict__ ws,
                          float* __restrict__ out)
{
  u16*  Bl   = (u16*)smem;                        // [32kc][4ngl][512]
  u16*  hlds = (u16*)(smem + 131072);             // 128 x 24
  float* wlds = (float*)(smem + 131072 + 6144);   // 4*16*6
  constexpr int RS = 24;
  const int tid = threadIdx.x, w = tid>>6, ln = tid&63, col = ln&15, quad = ln>>4;
  const int bi2 = blk2 & 3, hj = blk2 >> 2, h0 = hj*16;
  const int bgA = bi2*8 + w, bgB = bgA + 4;

  const u16* Upak = (const u16*)(ws + OFF_UW2P);
  const u16* H1r  = (const u16*)(ws + OFF_H1);
  const u16* H2r  = (const u16*)(ws + OFF_H2);
  u16* Hw = (u16*)(ws + OFF_H2);
  int* flags = (int*)(ws + OFF_FLAGS);
  int* d1a = flags + (2*bi2)*FSTRIDE;
  int* d1b = flags + (2*bi2+1)*FSTRIDE;
  int* done2 = flags + 1024 + bi2*FSTRIDE;

  #pragma unroll
  for (int p=0;p<32;p++){
    int pid = w*32 + p, kc = pid>>2, ngl = pid&3;
    int ng = ngl*32 + hj;
    async_cp16(Upak + ((size_t)(kc*128+ng)*64 + ln)*8, Bl + (size_t)pid*512);
  }
  for (int idx=tid; idx<4*16*6; idx+=256){
    int gate = idx/96, rem = idx%96, hcol = rem/6, k = rem%6;
    int gcol = gate*512 + h0 + hcol;
    wlds[idx] = (k==0)? bias[gcol] : (k<=4 ? V[(size_t)(k-1)*2048 + gcol] : 0.f);
  }
  const float fcwr = fcw[h0 + col];

  float c[8];
  #pragma unroll
  for (int i=0;i<8;i++) c[i] = 0.f;
  const f32x4 vzero = {0.f,0.f,0.f,0.f};

  for (int t=0; t<T_; t++){
    if (tid==0){
      spin_ge(d1a, 16*(t+1));                 // h1[t] ready (both L1 bi halves)
      spin_ge(d1b, 16*(t+1));
      if (t>0) spin_ge(done2, 32*t);          // own cohort: h2[t-1] ready
      __builtin_amdgcn_fence(__ATOMIC_ACQUIRE, "agent");   // once/step buffer_inv
    }
    __syncthreads();   // barrier 1

    f32x4 accA[4], accB[4];
    #pragma unroll
    for (int i=0;i<4;i++){ accA[i] = vzero; accB[i] = vzero; }

    const u16* A1 = H1r + (size_t)(t&7)*H_SLOT;
    if (t > 0){
      const u16* A2 = H2r + (size_t)((t-1)&1)*H_SLOT;
      l2_kloop<32>(accA, accB, Bl, A1, A2, bgA, bgB, ln);
    } else {
      l2_kloop<16>(accA, accB, Bl, A1, A1, bgA, bgB, ln);
    }

    // epilogue
    float wv[4][5];
    #pragma unroll
    for (int gate=0; gate<4; gate++){
      const float* wp = wlds + (size_t)(gate*16 + col)*6;
      #pragma unroll
      for (int k=0;k<5;k++) wv[gate][k] = wp[k];
    }
    float fcp[2][4];
    #pragma unroll
    for (int sel=0; sel<2; sel++){
      const f32x4* ac = sel ? accB : accA;
      #pragma unroll
      for (int r=0;r<4;r++){
        const float* ip = inp + ((size_t)(bi2*128 + sel*64 + w*16 + quad*4 + r)*T_ + t)*5;
        float i0=ip[0], i1=ip[1], i2=ip[2], i3=ip[3];
        float gv[4];
        #pragma unroll
        for (int gate=0; gate<4; gate++){
          gv[gate] = ac[gate][r] + wv[gate][0]
                   + i0*wv[gate][1] + i1*wv[gate][2] + i2*wv[gate][3] + i3*wv[gate][4];
        }
        float ig=sigm_f(gv[0]), fg=sigm_f(gv[1]), gg=tanh_ff(gv[2]), og=sigm_f(gv[3]);
        float cn = fg*c[sel*4+r] + ig*gg;
        c[sel*4+r] = cn;
        float h = og*tanh_ff(cn);
        fcp[sel][r] = h*fcwr;
        hlds[(size_t)(sel*64 + w*16 + quad*4 + r)*RS + col] = f2bf(h);
      }
    }
    #pragma unroll
    for (int sel=0; sel<2; sel++){
      #pragma unroll
      for (int r=0;r<4;r++){
        float v = fcp[sel][r];
        #pragma unroll
        for (int m=1;m<16;m<<=1) v += __shfl_xor(v, m, 16);
        if (col == 0)
          atomicAdd(&out[(size_t)(bi2*128 + sel*64 + w*16 + quad*4 + r)*T_ + t], v);
      }
    }
    // pack: same-wave transpose. Block cols = half a kc tile (kc=hj>>1, half hj&1)
    {
      int sel = ln>>5, ch = (ln>>4)&1, m = ln&15;
      uint4 v = *(const uint4*)&hlds[(size_t)(sel*64 + w*16 + m)*RS + ch*8];
      int lp = ((hj&1)*2 + ch)*16 + m;
      int bgx = bi2*8 + sel*4 + w;
      ring_st16(Hw + (size_t)(t&1)*H_SLOT + ((size_t)(bgx*16 + (hj>>1))*64 + lp)*8, v);
    }
    __syncthreads();   // barrier 2
    if (tid==0){
      __builtin_amdgcn_fence(__ATOMIC_RELEASE, "workgroup");
      __hip_atomic_fetch_add(done2, 1, __ATOMIC_RELAXED, __HIP_MEMORY_SCOPE_AGENT);
    }
  }
}

__global__ void __launch_bounds__(256, 1)
lstm_main_v6(const float* __restrict__ inp, const float* __restrict__ W1,
             const float* __restrict__ V1, const float* __restrict__ b1,
             const float* __restrict__ V2, const float* __restrict__ b2,
             const float* __restrict__ fcw, char* __restrict__ ws, float* __restrict__ out)
{
  extern __shared__ char smem[];
  int blk = blockIdx.x;
  if (blk < 128) run_l1_v6(smem, blk, inp, W1, V1, b1, ws);
  else           run_l2_v6(smem, blk-128, inp, V2, b2, fcw, ws, out);
}

// ===================== v5 fallback (proven 2582us path) ======================
template<int LAYER>
__device__ __forceinline__ void stage_B(u16* buf, const u16* __restrict__ Upak,
                                        int hj, int g, int w, int ln)
{
  constexpr int NGW = (LAYER==1)?16:8;
  constexpr int GKC = (LAYER==1)?2:4;
  #pragma unroll
  for (int p=0;p<8;p++){
    int pid = w*8 + p;
    int kci = pid / NGW;
    int ngl = pid % NGW;
    int gate = ngl / (NGW/4);
    int sub  = ngl % (NGW/4);
    int ng   = gate*32 + hj*(NGW/4) + sub;
    int kc   = g*GKC + kci;
    const u16* src = Upak + ((size_t)(kc*128 + ng)*64 + ln)*8;
    u16* dst = buf + (size_t)(kci*NGW + ngl)*512;
    async_cp16(src, dst);
  }
}

template<int LAYER>
__device__ __forceinline__ void preload_A(bf16x8* areg, const u16* __restrict__ A1,
                                          const u16* __restrict__ A2, int bg, int g, int ln)
{
  constexpr int GKC = (LAYER==1)?2:4;
  #pragma unroll
  for (int kci=0;kci<GKC;kci++){
    int kc = g*GKC + kci;
    const u16* base = A1; int kcl = kc;
    if (LAYER==2 && kc >= 16){ base = A2; kcl = kc - 16; }
    areg[kci] = ring_ld16(base + ((size_t)bg*16 + kcl)*512 + (size_t)ln*8);
  }
}

template<int LAYER>
__device__ void run_layer(u16 (*Bbuf)[16384], int blk,
                          const float* __restrict__ inp,
                          const float* __restrict__ W1,
                          const float* __restrict__ V,
                          const float* __restrict__ bias,
                          const float* __restrict__ fcw,
                          char* __restrict__ ws,
                          float* __restrict__ out)
{
  constexpr int HT  = (LAYER==1)?64:32;
  constexpr int HGN = (LAYER==1)?4:2;
  constexpr int NGW = (LAYER==1)?16:8;
  constexpr int GKC = (LAYER==1)?2:4;
  constexpr int RS  = (LAYER==1)?72:40;
  constexpr int KCP = (LAYER==1)?2:1;
  constexpr int NPIECE = 4*KCP;

  const int tid = threadIdx.x;
  const int w    = tid >> 6;
  const int ln   = tid & 63;
  const int col  = ln & 15;
  const int quad = ln >> 4;
  const int bi = (LAYER==1) ? (blk >> 3) : ((blk-64) >> 4);
  const int hj = (LAYER==1) ? (blk & 7)  : ((blk-64) & 15);
  const int h0 = hj * HT;
  const int bg = bi*4 + w;

  const u16* Upak = (const u16*)(ws + ((LAYER==1)?OFF_U1P:OFF_UW2P));
  const u16* H1r  = (const u16*)(ws + OFF_H1);
  const u16* H2r  = (const u16*)(ws + OFF_H2);
  u16* Hw  = (u16*)(ws + ((LAYER==1)?OFF_H1:OFF_H2));
  int* done1 = (int*)(ws + OFF_FLAGS);
  int* done2 = (int*)(ws + OFF_FLAGS) + 1024;
  u16* hlds  = &Bbuf[0][0];

  float fcwr[HGN];
  if (LAYER==2){
    #pragma unroll
    for (int hg=0; hg<HGN; hg++) fcwr[hg] = fcw[h0 + hg*16 + col];
  }
  float c[HGN*4];
  #pragma unroll
  for (int i=0;i<HGN*4;i++) c[i] = 0.f;
  const f32x4 vzero = {0.f,0.f,0.f,0.f};

  if (LAYER==2) stage_B<LAYER>(Bbuf[0], Upak, hj, 0, w, ln);

  for (int t=0; t<T_; t++){
    if (tid == 0){
      if (LAYER==1){
        if (t > 0)      spin_ge(&done1[bi*FSTRIDE], 8*t);
        if (t >= NRING) spin_ge(&done2[bi*FSTRIDE], 16*(t-NRING+1));
      } else {
        spin_ge(&done1[bi*FSTRIDE], 8*(t+1));
        if (t > 0) spin_ge(&done2[bi*FSTRIDE], 16*t);
      }
      __builtin_amdgcn_fence(__ATOMIC_ACQUIRE, "workgroup");
    }
    __syncthreads();

    f32x4 acc[NGW];
    #pragma unroll
    for (int i=0;i<NGW;i++) acc[i] = vzero;

    const int ngroups = (LAYER==1) ? (t>0 ? 8 : 0) : (t>0 ? 8 : 4);
    if (ngroups > 0){
      const u16* A1; const u16* A2 = nullptr;
      if (LAYER==1) A1 = H1r + (size_t)((t-1)%NRING)*H_SLOT;
      else { A1 = H1r + (size_t)(t%NRING)*H_SLOT;
             if (t>0) A2 = H2r + (size_t)((t-1)&1)*H_SLOT; }

      bf16x8 acur[GKC], anxt[GKC];
      preload_A<LAYER>(acur, A1, A2, bg, 0, ln);
      __syncthreads();
      for (int g=0; g<ngroups; g++){
        if (g+1 < ngroups){
          stage_B<LAYER>(Bbuf[(g+1)&1], Upak, hj, g+1, w, ln);
          preload_A<LAYER>(anxt, A1, A2, bg, g+1, ln);
        }
        #pragma unroll
        for (int kci=0; kci<GKC; kci++){
          const bf16x8 ah = acur[kci];
          #pragma unroll
          for (int ngl=0; ngl<NGW; ngl++){
            const bf16x8 bf = *(const bf16x8*)&Bbuf[g&1][(size_t)(kci*NGW+ngl)*512 + ln*8];
            acc[ngl] = __builtin_amdgcn_mfma_f32_16x16x32_bf16(ah, bf, acc[ngl], 0, 0, 0);
          }
        }
        #pragma unroll
        for (int i=0;i<GKC;i++) acur[i] = anxt[i];
        __syncthreads();
      }
    }

    float inv[4][5];
    #pragma unroll
    for (int r=0;r<4;r++){
      const float* ip = inp + ((size_t)(bi*64 + w*16 + quad*4 + r)*T_ + t)*5;
      #pragma unroll
      for (int k=0;k<5;k++) inv[r][k] = ip[k];
    }
    float fcp[4] = {0.f,0.f,0.f,0.f};
    #pragma unroll
    for (int hg=0; hg<HGN; hg++){
      float wv[4][6];
      #pragma unroll
      for (int gate=0; gate<4; gate++){
        int gcol = gate*512 + h0 + hg*16 + col;
        wv[gate][0] = bias[gcol];
        wv[gate][1] = V[gcol];
        wv[gate][2] = V[2048 + gcol];
        wv[gate][3] = V[4096 + gcol];
        wv[gate][4] = V[6144 + gcol];
        wv[gate][5] = (LAYER==1) ? W1[gcol] : 0.f;
      }
      #pragma unroll
      for (int r=0;r<4;r++){
        float gv[4];
        #pragma unroll
        for (int gate=0; gate<4; gate++){
          float p = wv[gate][0]
                  + inv[r][0]*wv[gate][1] + inv[r][1]*wv[gate][2]
                  + inv[r][2]*wv[gate][3] + inv[r][3]*wv[gate][4];
          if (LAYER==1) p += inv[r][4]*wv[gate][5];
          gv[gate] = acc[gate*HGN + hg][r] + p;
        }
        float ig = sigm(gv[0]);
        float fg = sigm(gv[1]);
        float gg = tanh_f(gv[2]);
        float og = sigm(gv[3]);
        float cn = fg*c[hg*4+r] + ig*gg;
        c[hg*4+r] = cn;
        float h = og*tanh_f(cn);
        if (LAYER==2) fcp[r] += h*fcwr[hg];
        int bl = w*16 + quad*4 + r;
        int hc = hg*16 + col;
        hlds[bl*RS + hc] = f2bf(h);
      }
    }
    if (LAYER==2){
      #pragma unroll
      for (int r=0;r<4;r++){
        #pragma unroll
        for (int m=1;m<16;m<<=1) fcp[r] += __shfl_xor(fcp[r], m, 16);
      }
      if (col == 0){
        #pragma unroll
        for (int r=0;r<4;r++)
          atomicAdd(&out[(size_t)(bi*64 + w*16 + quad*4 + r)*T_ + t], fcp[r]);
      }
    }
    __syncthreads();

    {
      u16* dst = Hw + (size_t)((LAYER==1) ? (t % NRING) : (t & 1))*H_SLOT;
      #pragma unroll
      for (int it=0; it<(NPIECE*64+255)/256; it++){
        int cidx = tid + it*256;
        if (cidx < NPIECE*64){
          int piece = cidx >> 6, lp = cidx & 63;
          int bgi, kci;
          if (LAYER==1){ bgi = (piece >> 1) & 3; kci = piece & 1; }
          else         { bgi = piece & 3;        kci = 0; }
          int row = bgi*16 + (lp & 15);
          int hc  = kci*32 + ((lp >> 4) << 3);
          uint4 v = *(const uint4*)&hlds[(size_t)row*RS + hc];
          int kcg = (LAYER==1) ? (hj*2 + kci) : hj;
          ring_st16(&dst[(((size_t)(bi*4 + bgi)*16 + kcg)*64 + lp)*8], v);
        }
      }
    }
    __syncthreads();
    if (tid == 0){
      __builtin_amdgcn_fence(__ATOMIC_RELEASE, "workgroup");
      int* dp = (LAYER==1) ? &done1[bi*FSTRIDE] : &done2[bi*FSTRIDE];
      __hip_atomic_fetch_add(dp, 1, __ATOMIC_RELAXED, __HIP_MEMORY_SCOPE_AGENT);
    }
    if (t+1 < T_) stage_B<LAYER>(Bbuf[0], Upak, hj, 0, w, ln);
  }
}

__global__ void __launch_bounds__(256, 1)
lstm_main_v5(const float* __restrict__ inp, const float* __restrict__ W1,
             const float* __restrict__ V1, const float* __restrict__ b1,
             const float* __restrict__ V2, const float* __restrict__ b2,
             const float* __restrict__ fcw, char* __restrict__ ws, float* __restrict__ out)
{
  __shared__ __align__(16) u16 Bbuf[2][16384];
  int blk = blockIdx.x;
  if (blk < 64) run_layer<1>(Bbuf, blk, inp, W1, V1, b1, nullptr, ws, out);
  else          run_layer<2>(Bbuf, blk, inp, nullptr, V2, b2, fcw, ws, out);
}

extern "C" void kernel_launch(void* const* d_in, const int* in_sizes, int n_in,
                              void* d_out, int out_size, void* d_ws, size_t ws_size,
                              hipStream_t stream) {
  const float* inp = (const float*)d_in[0];
  const float* W1  = (const float*)d_in[1];
  const float* U1  = (const float*)d_in[2];
  const float* V1  = (const float*)d_in[3];
  const float* b1  = (const float*)d_in[4];
  const float* W2  = (const float*)d_in[5];
  const float* U2  = (const float*)d_in[6];
  const float* V2  = (const float*)d_in[7];
  const float* b2  = (const float*)d_in[8];
  const float* fcw = (const float*)d_in[9];
  const float* fcb = (const float*)d_in[10];
  char* ws = (char*)d_ws;
  float* out = (float*)d_out;

  pack_w_kernel<<<1536, 256, 0, stream>>>(U1, W2, U2,
      (u16*)(ws + OFF_U1P), (u16*)(ws + OFF_UW2P));
  init_kernel<<<(B_*T_ + 255)/256, 256, 0, stream>>>(out, fcb, (int*)(ws + OFF_FLAGS));

  int dev = 0; (void)hipGetDevice(&dev);
  int maxShm = 0;
  (void)hipDeviceGetAttribute(&maxShm, hipDeviceAttributeMaxSharedMemoryPerBlock, dev);
  if (maxShm >= SMEM_V6) {
    (void)hipFuncSetAttribute((const void*)lstm_main_v6,
                              hipFuncAttributeMaxDynamicSharedMemorySize, SMEM_V6);
    lstm_main_v6<<<256, 256, SMEM_V6, stream>>>(inp, W1, V1, b1, V2, b2, fcw, ws, out);
  } else {
    lstm_main_v5<<<192, 256, 0, stream>>>(inp, W1, V1, b1, V2, b2, fcw, ws, out);
  }
}